// Round 6
// baseline (281.577 us; speedup 1.0000x reference)
//
#include <hip/hip_runtime.h>

// Transformer-XL relative multi-head attention, MI355X (gfx950).
// Round 5: attn 4-way j-split (4 blocks/CU, zero extra traffic) + XCD-chunked
// block swizzle (L2 locality for K/V/R) + scale folded into Q projection.
// GEMM structure unchanged from round 4 (m97-style, neutral at these shapes).

#define B_SZ 2
#define QLEN 1024
#define MLEN 1024
#define KLEN 2048
#define DMODEL 1024
#define NH 16
#define DH 64
#define NSPLIT 4

typedef _Float16 f16;
typedef __attribute__((ext_vector_type(8))) _Float16 f16x8;
typedef __attribute__((ext_vector_type(4))) _Float16 f16x4;
typedef __attribute__((ext_vector_type(4))) float f32x4;

__device__ __forceinline__ f16 f2h(float v) { return (f16)v; }
__device__ __forceinline__ float h2f(f16 v) { return (float)v; }

__device__ __forceinline__ f32x4 mfma16(f16x8 a, f16x8 b, f32x4 c) {
  return __builtin_amdgcn_mfma_f32_16x16x32_f16(a, b, c, 0, 0, 0);
}

__device__ __forceinline__ void gload_lds16(const f16* g, f16* l) {
  __builtin_amdgcn_global_load_lds(
      (const __attribute__((address_space(1))) void*)g,
      (__attribute__((address_space(3))) void*)l, 16, 0, 0);
}

__device__ __forceinline__ float bperm(int srclane, float v) {
  return __int_as_float(
      __builtin_amdgcn_ds_bpermute(srclane << 2, __float_as_int(v)));
}

// ---------------- pack ----------------
__global__ __launch_bounds__(256) void convert_kernel(const float* __restrict__ src,
                                                      f16* __restrict__ dst, int n4) {
  const int i = blockIdx.x * 256 + threadIdx.x;
  if (i >= n4) return;
  const float4 v = reinterpret_cast<const float4*>(src)[i];
  f16x4 o = {(f16)v.x, (f16)v.y, (f16)v.z, (f16)v.w};
  reinterpret_cast<f16x4*>(dst)[i] = o;
}

__global__ __launch_bounds__(256) void pack_weights_kernel(
    const float* __restrict__ Wq, const float* __restrict__ Wk,
    const float* __restrict__ Wv, const float* __restrict__ Wr,
    const float* __restrict__ Wo, f16* __restrict__ Wqb, f16* __restrict__ Wkb,
    f16* __restrict__ Wvb, f16* __restrict__ Wrb, f16* __restrict__ Wob) {
  const float* src;
  f16* dst;
  switch (blockIdx.y) {
    case 0: src = Wq; dst = Wqb; break;
    case 1: src = Wk; dst = Wkb; break;
    case 2: src = Wv; dst = Wvb; break;
    case 3: src = Wr; dst = Wrb; break;
    default: src = Wo; dst = Wob; break;
  }
  const int i = blockIdx.x * 256 + threadIdx.x;
  const float4 v = reinterpret_cast<const float4*>(src)[i];
  f16x4 o = {(f16)v.x, (f16)v.y, (f16)v.z, (f16)v.w};
  reinterpret_cast<f16x4*>(dst)[i] = o;
}

__global__ __launch_bounds__(256) void build_kin_kernel(const float* __restrict__ x,
                                                        const float* __restrict__ mem,
                                                        f16* __restrict__ kin,
                                                        f16* __restrict__ xb) {
  const int i = blockIdx.x * 256 + threadIdx.x;
  const int per_b = KLEN * DMODEL / 4;
  const int b = i / per_b;
  const int rem = i - b * per_b;
  const int row = rem / (DMODEL / 4);
  const int cc = (rem - row * (DMODEL / 4)) * 4;
  const float* src = (row < MLEN)
      ? mem + ((size_t)b * MLEN + row) * DMODEL + cc
      : x + ((size_t)b * QLEN + (row - MLEN)) * DMODEL + cc;
  const float4 v = *reinterpret_cast<const float4*>(src);
  f16x4 o = {(f16)v.x, (f16)v.y, (f16)v.z, (f16)v.w};
  *reinterpret_cast<f16x4*>(kin + (size_t)i * 4) = o;
  if (row >= MLEN)
    *reinterpret_cast<f16x4*>(&xb[((size_t)b * QLEN + (row - MLEN)) * DMODEL + cc]) = o;
}

// ------------- GEMM core (m97 structure): C[M,1024] = A[M,1024].B[1024,1024]^T -------
// 128x128 tile, 4 waves, BK=64, linear LDS + both-sides XOR swizzle.
// DUAL epilogue also folds the attention scale (1/8) into Q outputs.
template <int DUAL, int OUT_F32>
__device__ __forceinline__ void gemm_core(const f16* __restrict__ A,
                                          const f16* __restrict__ Bm,
                                          void* __restrict__ C0v,
                                          void* __restrict__ C1v,
                                          const float* __restrict__ bias0,
                                          const float* __restrict__ bias1, int bm,
                                          int bn) {
  const int tid = threadIdx.x;
  const int wave = tid >> 6, lane = tid & 63;
  const int wr = wave >> 1, wc = wave & 1;
  const int lr = lane & 15, hi = lane >> 4;

  __shared__ f16 As[128 * 64];
  __shared__ f16 Bs[128 * 64];

  f32x4 acc[4][4];
#pragma unroll
  for (int m = 0; m < 4; ++m)
#pragma unroll
    for (int n = 0; n < 4; ++n) acc[m][n] = f32x4{0.f, 0.f, 0.f, 0.f};

  for (int k0 = 0; k0 < DMODEL; k0 += 64) {
    __syncthreads();
#pragma unroll
    for (int it = 0; it < 4; ++it) {
      const int c = it * 256 + tid;
      const int row = c >> 3, c16 = c & 7;
      const int c16s = c16 ^ (row & 7);
      gload_lds16(&A[(size_t)(bm + row) * DMODEL + k0 + c16s * 8], &As[c * 8]);
      gload_lds16(&Bm[(size_t)(bn + row) * DMODEL + k0 + c16s * 8], &Bs[c * 8]);
    }
    __syncthreads();
#pragma unroll
    for (int kk = 0; kk < 2; ++kk) {
      f16x8 af[4], bf[4];
#pragma unroll
      for (int m = 0; m < 4; ++m) {
        const int row = wr * 64 + m * 16 + lr;
        const int colf = (kk * 32 + hi * 8) ^ ((row & 7) << 3);
        af[m] = *reinterpret_cast<const f16x8*>(&As[row * 64 + colf]);
      }
#pragma unroll
      for (int n = 0; n < 4; ++n) {
        const int row = wc * 64 + n * 16 + lr;
        const int colf = (kk * 32 + hi * 8) ^ ((row & 7) << 3);
        bf[n] = *reinterpret_cast<const f16x8*>(&Bs[row * 64 + colf]);
      }
#pragma unroll
      for (int m = 0; m < 4; ++m)
#pragma unroll
        for (int n = 0; n < 4; ++n) acc[m][n] = mfma16(af[m], bf[n], acc[m][n]);
    }
  }

#pragma unroll
  for (int m = 0; m < 4; ++m)
#pragma unroll
    for (int n = 0; n < 4; ++n)
#pragma unroll
      for (int r = 0; r < 4; ++r) {
        const int grow = bm + wr * 64 + m * 16 + hi * 4 + r;
        const int gcol = bn + wc * 64 + n * 16 + lr;
        const float v = acc[m][n][r];
        if constexpr (OUT_F32) {
          reinterpret_cast<float*>(C0v)[(size_t)grow * DMODEL + gcol] = v;
        } else if constexpr (DUAL) {
          reinterpret_cast<f16*>(C0v)[(size_t)grow * DMODEL + gcol] =
              f2h((v + bias0[gcol]) * 0.125f);
          reinterpret_cast<f16*>(C1v)[(size_t)grow * DMODEL + gcol] =
              f2h((v + bias1[gcol]) * 0.125f);
        } else {
          reinterpret_cast<f16*>(C0v)[(size_t)grow * DMODEL + gcol] = f2h(v);
        }
      }
}

// y<16: Q (dual, +bias, x1/8), y<48: K, y<80: V, else R.
__global__ __launch_bounds__(256) void proj_kernel(
    const f16* __restrict__ Xb, const f16* __restrict__ Kin,
    const f16* __restrict__ Pos, const f16* __restrict__ Wqb,
    const f16* __restrict__ Wkb, const f16* __restrict__ Wvb,
    const f16* __restrict__ Wrb, f16* __restrict__ Qwb, f16* __restrict__ Qrb,
    f16* __restrict__ Kbb, f16* __restrict__ Vbb, f16* __restrict__ Rbb,
    const float* __restrict__ rwb, const float* __restrict__ rrb) {
  const int y = blockIdx.y;
  const int bn = blockIdx.x * 128;
  if (y < 16) {
    gemm_core<1, 0>(Xb, Wqb, Qwb, Qrb, rwb, rrb, y * 128, bn);
  } else if (y < 48) {
    gemm_core<0, 0>(Kin, Wkb, Kbb, nullptr, nullptr, nullptr, (y - 16) * 128, bn);
  } else if (y < 80) {
    gemm_core<0, 0>(Kin, Wvb, Vbb, nullptr, nullptr, nullptr, (y - 48) * 128, bn);
  } else {
    gemm_core<0, 0>(Pos, Wrb, Rbb, nullptr, nullptr, nullptr, (y - 80) * 128, bn);
  }
}

__global__ __launch_bounds__(256) void gemm_out_kernel(const f16* __restrict__ A,
                                                       const f16* __restrict__ Bm,
                                                       float* __restrict__ C) {
  gemm_core<0, 1>(A, Bm, C, nullptr, nullptr, nullptr, blockIdx.y * 128,
                  blockIdx.x * 128);
}

// ---------------- fused attention (4-way j-split, XCD-chunked) ----------------
// 1D grid of 1024 blocks; decode puts all 32 blocks of 4 (b,head) groups on one
// XCD (bid&7) so K/V/R stay L2-resident. Block: 512 thr = 8 waves x 16 q-rows.
// Per 64-key tile: T14 split staging; S = Qw.K^T; BD = Qr.R_win^T rel-shifted
// via ds_bpermute; online softmax (scale pre-folded into Qw/Qr); P->per-wave
// LDS; O += P.V. Emits unnormalized O (f32) + (m,l) per split.
__global__ __launch_bounds__(512) void attn_kernel(
    const f16* __restrict__ Qw, const f16* __restrict__ Qr,
    const f16* __restrict__ Kb, const f16* __restrict__ Vb,
    const f16* __restrict__ Rb, float* __restrict__ Opart,
    float2* __restrict__ MLp) {
  // XCD-chunked decode: xcd = bid&7 owns groups 4*xcd..4*xcd+3 (group = b*16+n)
  const int bid = blockIdx.x;
  const int xcd = bid & 7, rr = bid >> 3;
  const int grp = xcd * 4 + (rr >> 5);
  const int ii = rr & 31;
  const int b = grp >> 4, n = grp & 15;
  const int qi = ii >> 2, split = ii & 3;

  const int qb = qi * 128;
  const int tid = threadIdx.x;
  const int wave = tid >> 6, lane = tid & 63;
  const int lr = lane & 15, hi = lane >> 4;
  const int t0 = hi * 4;
  const int w0 = qb + wave * 16;

  const int T = (qb + 128 + MLEN) >> 6;
  const int jt_beg = (split * T) >> 2;
  const int jt_end = ((split + 1) * T) >> 2;

  __shared__ f16 Ks[64][72];
  __shared__ f16 Vs[64][72];
  __shared__ f16 Ps[8][16][72];

  f16x8 qw[2], qr[2];
  {
    const size_t qbase = ((size_t)(b * QLEN + w0 + lr)) * DMODEL + n * DH;
#pragma unroll
    for (int kk = 0; kk < 2; ++kk) {
      qw[kk] = *reinterpret_cast<const f16x8*>(&Qw[qbase + kk * 32 + hi * 8]);
      qr[kk] = *reinterpret_cast<const f16x8*>(&Qr[qbase + kk * 32 + hi * 8]);
    }
  }

  f32x4 o[4];
#pragma unroll
  for (int df = 0; df < 4; ++df) o[df] = f32x4{0.f, 0.f, 0.f, 0.f};
  float mrow[4], lrow[4];
#pragma unroll
  for (int r = 0; r < 4; ++r) { mrow[r] = -1e30f; lrow[r] = 0.f; }

  const f16* Rn = Rb + n * DH;

  const int krow = tid >> 3, kc8 = (tid & 7) << 3;
  const int vrow = tid & 63, vc8 = ((tid >> 6) & 7) << 3;
  f16x8 kreg, vreg;
  auto issue = [&](int jt) {
    const size_t kvb = ((size_t)(b * KLEN + (jt << 6))) * DMODEL + n * DH;
    kreg = *reinterpret_cast<const f16x8*>(&Kb[kvb + (size_t)krow * DMODEL + kc8]);
    vreg = *reinterpret_cast<const f16x8*>(&Vb[kvb + (size_t)vrow * DMODEL + vc8]);
  };
  auto commit = [&]() {
    *reinterpret_cast<f16x8*>(&Ks[krow][kc8]) = kreg;
#pragma unroll
    for (int e = 0; e < 8; ++e) Vs[vc8 + e][vrow] = vreg[e];
  };

  issue(jt_beg);
  commit();
  __syncthreads();

  for (int jt = jt_beg; jt < jt_end; ++jt) {
    const bool hn = (jt + 1 < jt_end);
    if (hn) issue(jt + 1);  // T14: loads in flight during compute

    const int j0 = jt << 6;

    // S = Qw . K^T  (scale pre-folded into Qw)
    f32x4 s[4];
#pragma unroll
    for (int nf = 0; nf < 4; ++nf) s[nf] = f32x4{0.f, 0.f, 0.f, 0.f};
#pragma unroll
    for (int kk = 0; kk < 2; ++kk)
#pragma unroll
      for (int nf = 0; nf < 4; ++nf) {
        const f16x8 kf =
            *reinterpret_cast<const f16x8*>(&Ks[nf * 16 + lr][kk * 32 + hi * 8]);
        s[nf] = mfma16(qw[kk], kf, s[nf]);
      }

    // BD over u in [u0, u0+80); clamp region == masked region
    const int u0 = j0 + QLEN - 16 - w0;
    f32x4 bd[5];
#pragma unroll
    for (int nt = 0; nt < 5; ++nt) bd[nt] = f32x4{0.f, 0.f, 0.f, 0.f};
#pragma unroll
    for (int nt = 0; nt < 5; ++nt) {
      const int u = u0 + nt * 16 + lr;
      const int uc = u < KLEN ? u : KLEN - 1;
#pragma unroll
      for (int kk = 0; kk < 2; ++kk) {
        const f16x8 rf = *reinterpret_cast<const f16x8*>(
            &Rn[(size_t)uc * DMODEL + kk * 32 + hi * 8]);
        bd[nt] = mfma16(qr[kk], rf, bd[nt]);
      }
    }

    // rel-shift via bpermute: slot (t=t0+r, j_local) needs u_local = j_local+15-t
#pragma unroll
    for (int r = 0; r < 4; ++r) {
      const int off = 15 - t0 - r;
      const int sl = lr + off;
      const int srclane = hi * 16 + (sl & 15);
      const bool cross = sl >= 16;
      const int i = w0 + t0 + r;
#pragma unroll
      for (int nf = 0; nf < 4; ++nf) {
        const float x0 = bperm(srclane, bd[nf][r]);
        const float x1 = bperm(srclane, bd[nf + 1][r]);
        const float bv = cross ? x1 : x0;
        const int j = j0 + nf * 16 + lr;
        s[nf][r] = (j <= i + MLEN) ? (s[nf][r] + bv) : -1e30f;
      }
    }

    // online softmax (rows on 16 lanes sharing hi)
#pragma unroll
    for (int r = 0; r < 4; ++r) {
      float tmax = fmaxf(fmaxf(s[0][r], s[1][r]), fmaxf(s[2][r], s[3][r]));
#pragma unroll
      for (int d = 1; d < 16; d <<= 1) tmax = fmaxf(tmax, __shfl_xor(tmax, d, 64));
      const float mnew = fmaxf(mrow[r], tmax);
      const float alpha = __expf(mrow[r] - mnew);
      mrow[r] = mnew;
      float tsum = 0.f;
#pragma unroll
      for (int nf = 0; nf < 4; ++nf) {
        const float p = __expf(s[nf][r] - mnew);
        s[nf][r] = p;
        tsum += p;
      }
#pragma unroll
      for (int d = 1; d < 16; d <<= 1) tsum += __shfl_xor(tsum, d, 64);
      lrow[r] = lrow[r] * alpha + tsum;
#pragma unroll
      for (int df = 0; df < 4; ++df) o[df][r] *= alpha;
    }

    // P -> per-wave LDS (same-wave handoff, proven barrier-free)
#pragma unroll
    for (int nf = 0; nf < 4; ++nf)
#pragma unroll
      for (int r = 0; r < 4; ++r) Ps[wave][t0 + r][nf * 16 + lr] = f2h(s[nf][r]);

#pragma unroll
    for (int kk = 0; kk < 2; ++kk) {
      const f16x8 pa =
          *reinterpret_cast<const f16x8*>(&Ps[wave][lr][kk * 32 + hi * 8]);
#pragma unroll
      for (int df = 0; df < 4; ++df) {
        const f16x8 vb =
            *reinterpret_cast<const f16x8*>(&Vs[df * 16 + lr][kk * 32 + hi * 8]);
        o[df] = mfma16(pa, vb, o[df]);
      }
    }

    __syncthreads();
    if (hn) commit();
    __syncthreads();
  }

  const size_t obase =
      (((size_t)(split * B_SZ + b) * NH + n) * QLEN + w0 + t0) * DH;
#pragma unroll
  for (int df = 0; df < 4; ++df)
#pragma unroll
    for (int r = 0; r < 4; ++r)
      Opart[obase + (size_t)r * DH + df * 16 + lr] = o[df][r];
  if (lr == 0) {
    const size_t mbase = ((size_t)(split * B_SZ + b) * NH + n) * QLEN + w0 + t0;
#pragma unroll
    for (int r = 0; r < 4; ++r) MLp[mbase + r] = float2{mrow[r], lrow[r]};
  }
}

__global__ __launch_bounds__(256) void combine_kernel(const float* __restrict__ Op,
                                                      const float2* __restrict__ ML,
                                                      f16* __restrict__ AV) {
  const int idx = blockIdx.x * 256 + threadIdx.x;  // (b,n,i,d4)
  const int d4 = idx & 15;
  const int i = (idx >> 4) & 1023;
  const int n = (idx >> 14) & 15;
  const int b = idx >> 18;
  size_t rs[NSPLIT];
  float2 ml[NSPLIT];
#pragma unroll
  for (int s = 0; s < NSPLIT; ++s) {
    rs[s] = ((size_t)((s * B_SZ + b) * NH + n)) * QLEN + i;
    ml[s] = ML[rs[s]];
  }
  float M = ml[0].x;
#pragma unroll
  for (int s = 1; s < NSPLIT; ++s) M = fmaxf(M, ml[s].x);
  float es[NSPLIT], l = 0.f;
#pragma unroll
  for (int s = 0; s < NSPLIT; ++s) {
    es[s] = __expf(ml[s].x - M);
    l += ml[s].y * es[s];
  }
  const float inv = 1.f / l;
  float4 acc = {0.f, 0.f, 0.f, 0.f};
#pragma unroll
  for (int s = 0; s < NSPLIT; ++s) {
    const float4 ov = *reinterpret_cast<const float4*>(&Op[rs[s] * DH + d4 * 4]);
    acc.x += ov.x * es[s];
    acc.y += ov.y * es[s];
    acc.z += ov.z * es[s];
    acc.w += ov.w * es[s];
  }
  f16x4 outv;
  outv[0] = f2h(acc.x * inv);
  outv[1] = f2h(acc.y * inv);
  outv[2] = f2h(acc.z * inv);
  outv[3] = f2h(acc.w * inv);
  *reinterpret_cast<f16x4*>(&AV[((size_t)(b * QLEN + i)) * DMODEL + n * DH + d4 * 4]) =
      outv;
}

// ---------------- launch ----------------
extern "C" void kernel_launch(void* const* d_in, const int* in_sizes, int n_in,
                              void* d_out, int out_size, void* d_ws, size_t ws_size,
                              hipStream_t stream) {
  (void)in_sizes; (void)n_in; (void)out_size; (void)ws_size;
  const float* x   = (const float*)d_in[0];
  const float* mem = (const float*)d_in[1];
  const float* pos = (const float*)d_in[2];
  const float* Wq  = (const float*)d_in[4];
  const float* Wk  = (const float*)d_in[5];
  const float* Wv  = (const float*)d_in[6];
  const float* Wr  = (const float*)d_in[7];
  const float* Wo  = (const float*)d_in[8];
  const float* rwb = (const float*)d_in[9];
  const float* rrb = (const float*)d_in[10];
  float* out = (float*)d_out;

  char* ws = (char*)d_ws;
  size_t off = 0;
  auto alloc = [&](size_t bytes) {
    void* p = (void*)(ws + off);
    off += (bytes + 255) & ~(size_t)255;
    return p;
  };
  f16* Xb  = (f16*)alloc((size_t)B_SZ * QLEN * DMODEL * 2);
  f16* Kin = (f16*)alloc((size_t)B_SZ * KLEN * DMODEL * 2);
  f16* Pos = (f16*)alloc((size_t)KLEN * DMODEL * 2);
  f16* Wqb = (f16*)alloc((size_t)DMODEL * DMODEL * 2);
  f16* Wkb = (f16*)alloc((size_t)DMODEL * DMODEL * 2);
  f16* Wvb = (f16*)alloc((size_t)DMODEL * DMODEL * 2);
  f16* Wrb = (f16*)alloc((size_t)DMODEL * DMODEL * 2);
  f16* Wob = (f16*)alloc((size_t)DMODEL * DMODEL * 2);
  f16* Qwb = (f16*)alloc((size_t)B_SZ * QLEN * DMODEL * 2);
  f16* Qrb = (f16*)alloc((size_t)B_SZ * QLEN * DMODEL * 2);
  f16* Kbb = (f16*)alloc((size_t)B_SZ * KLEN * DMODEL * 2);
  f16* Vbb = (f16*)alloc((size_t)B_SZ * KLEN * DMODEL * 2);
  f16* Rbb = (f16*)alloc((size_t)KLEN * DMODEL * 2);
  f16* AVb = (f16*)alloc((size_t)B_SZ * QLEN * DMODEL * 2);
  float*  Opart = (float*)alloc((size_t)NSPLIT * B_SZ * NH * QLEN * DH * 4);
  float2* MLp   = (float2*)alloc((size_t)NSPLIT * B_SZ * NH * QLEN * 8);

  pack_weights_kernel<<<dim3(1024, 5), dim3(256), 0, stream>>>(
      Wq, Wk, Wv, Wr, Wo, Wqb, Wkb, Wvb, Wrb, Wob);
  convert_kernel<<<dim3(KLEN * DMODEL / 4 / 256), dim3(256), 0, stream>>>(
      pos, Pos, KLEN * DMODEL / 4);
  build_kin_kernel<<<dim3(B_SZ * KLEN * DMODEL / 4 / 256), dim3(256), 0, stream>>>(
      x, mem, Kin, Xb);

  proj_kernel<<<dim3(8, 96), dim3(256), 0, stream>>>(
      Xb, Kin, Pos, Wqb, Wkb, Wvb, Wrb, Qwb, Qrb, Kbb, Vbb, Rbb, rwb, rrb);

  // 1024 blocks = 8 XCD chunks x 4 (b,n) groups x 32 (qi,split)
  attn_kernel<<<dim3(QLEN / 128 * NSPLIT * NH * B_SZ), dim3(512), 0, stream>>>(
      Qwb, Qrb, Kbb, Vbb, Rbb, Opart, MLp);

  combine_kernel<<<dim3(B_SZ * NH * QLEN * (DH / 4) / 256), dim3(256), 0, stream>>>(
      Opart, MLp, AVb);

  gemm_out_kernel<<<dim3(DMODEL / 128, B_SZ * QLEN / 128), dim3(256), 0, stream>>>(
      AVb, Wob, out);
}